// Round 1
// baseline (145.586 us; speedup 1.0000x reference)
//
#include <hip/hip_runtime.h>

// EfficientCrossAttentionHead: B=4, N=16384, C=256, H=64, fp32 in/out.
// Pipeline:
//   kW_pack : weights -> bf16 MFMA B-fragment layout in ws
//   kA_proj : x -> (k,q,v) via MFMA; q logits -> ws; partial (sum exp(k)*v, sum exp(k)) per block
//   kB_reduce: partials -> w[b][s][64][64] = (sum e*v)/Z
//   kC_out  : out = softmax_row(q_s) @ w_{1-s}
// Needs ws_size >= ~42.5 MB.

#define B_ 4
#define N_ 16384
#define C_ 256

typedef float f32x4 __attribute__((ext_vector_type(4)));
typedef __bf16 bf16x8 __attribute__((ext_vector_type(8)));

__device__ __forceinline__ unsigned short f2bf(float f) {
  union { float f; unsigned u; } v; v.f = f;
  return (unsigned short)((v.u + 0x7FFFu + ((v.u >> 16) & 1u)) >> 16);
}

// ws byte offsets
#define WPACK_OFF 0u           // [2][12][8][64][8] bf16 = 196608 B
#define Q_OFF     262144u      // q logits fp32 [8][16384][64] = 32 MB
#define PNW_OFF   33816576u    // partial nw [8][64][4096] f32 = 8 MB
#define PZ_OFF    42205184u    // partial z  [8][64][64]  f32 = 128 KB
#define WFIN_OFF  42336256u    // w final [8][4096] f32 = 128 KB

__global__ __launch_bounds__(256) void kW_pack(
    const float* __restrict__ Wk0, const float* __restrict__ Wk1,
    const float* __restrict__ Wq0, const float* __restrict__ Wq1,
    const float* __restrict__ Wv0, const float* __restrict__ Wv1,
    unsigned short* __restrict__ wpack) {
  int t = blockIdx.x * 256 + threadIdx.x;  // [0, 98304)
  int i = t & 7;
  int lane = (t >> 3) & 63;
  int q = t >> 9;            // [0,192)
  int ks = q & 7;
  int sj = q >> 3;           // [0,24)
  int s = sj / 12;
  int j = sj - s * 12;       // global col-frag 0..11 (k:0-3, q:4-7, v:8-11)
  int gc = 16 * j + (lane & 15);
  int c = 32 * ks + ((lane >> 4) << 3) + i;
  int m = gc >> 6, row = gc & 63;
  const float* W;
  if (s == 0) W = (m == 0) ? Wk0 : (m == 1) ? Wq0 : Wv0;
  else        W = (m == 0) ? Wk1 : (m == 1) ? Wq1 : Wv1;
  wpack[t] = f2bf(W[row * 256 + c]);
}

__global__ __launch_bounds__(256, 2) void kA_proj(
    const float* __restrict__ x0, const float* __restrict__ x1,
    const unsigned short* __restrict__ wpack,
    float* __restrict__ qbuf, float* __restrict__ pnw, float* __restrict__ pz) {
  int pb = blockIdx.x;       // 0..63 partial slot
  int bs = blockIdx.y;       // 0..7 : b = bs>>1, s = bs&1
  int b = bs >> 1, s = bs & 1;
  const float* x = (s ? x1 : x0) + (size_t)b * N_ * C_;
  int t = threadIdx.x;
  int w = t >> 6;            // wave 0..3; owns output cols [48w, 48w+48)
  int l = t & 63;
  int l15 = l & 15, lg = l >> 4;

  __shared__ unsigned short xs[64 * 256];  // 32 KB, bf16, XOR-swizzled rows
  __shared__ unsigned short pT[64 * 64];   // exp(k) transposed [h][n], swizzled
  __shared__ unsigned short vT[64 * 64];   // v transposed [d][n], swizzled
  char* xsb = (char*)xs;
  char* pTb = (char*)pT;
  char* vTb = (char*)vT;

  // B-fragments (weights) resident in registers: wave w covers j = 3w..3w+2
  bf16x8 bfr[3][8];
  {
    const char* wpb = (const char*)wpack;
#pragma unroll
    for (int jj = 0; jj < 3; ++jj)
#pragma unroll
      for (int ks = 0; ks < 8; ++ks) {
        int j = w * 3 + jj;
        size_t off = ((((size_t)s * 12 + j) * 8 + ks) * 64 + l) * 16;
        bfr[jj][ks] = *(const bf16x8*)(wpb + off);
      }
  }

  f32x4 nwacc[4];
#pragma unroll
  for (int j2 = 0; j2 < 4; ++j2) { f32x4 z = {0.f,0.f,0.f,0.f}; nwacc[j2] = z; }
  float zacc[3] = {0.f, 0.f, 0.f};

  for (int it = 0; it < 4; ++it) {
    int n0 = (pb + it * 64) * 64;  // token base within (b,s)

    // stage x tile [64][256] fp32 -> bf16 LDS (swizzle: byte ^= (row&7)<<4)
    const f32x4* xsrc = (const f32x4*)(x + (size_t)n0 * C_);
#pragma unroll
    for (int i = 0; i < 16; ++i) {
      int f = t + 256 * i;        // float4 index; row = f>>6
      int row = f >> 6;
      f32x4 v = xsrc[f];
      ushort4 pk;
      pk.x = f2bf(v[0]); pk.y = f2bf(v[1]); pk.z = f2bf(v[2]); pk.w = f2bf(v[3]);
      int off = (f * 8) ^ ((row & 7) << 4);
      *(ushort4*)(xsb + off) = pk;
    }
    __syncthreads();

    // phase 1: [64 tok][256] @ [256][192] -> k|q|v
    f32x4 acc[4][3];
#pragma unroll
    for (int rf = 0; rf < 4; ++rf)
#pragma unroll
      for (int jj = 0; jj < 3; ++jj) { f32x4 z = {0.f,0.f,0.f,0.f}; acc[rf][jj] = z; }
    for (int ks = 0; ks < 8; ++ks) {
      bf16x8 a[4];
#pragma unroll
      for (int rf = 0; rf < 4; ++rf) {
        int row = rf * 16 + l15;
        int off = (row * 512 + ks * 64 + lg * 16) ^ ((row & 7) << 4);
        a[rf] = *(const bf16x8*)(xsb + off);
      }
#pragma unroll
      for (int jj = 0; jj < 3; ++jj)
#pragma unroll
        for (int rf = 0; rf < 4; ++rf)
          acc[rf][jj] = __builtin_amdgcn_mfma_f32_16x16x32_bf16(
              a[rf], bfr[jj][ks], acc[rf][jj], 0, 0, 0);
    }

    // fragment processing: k -> exp -> pT + z ; q -> global ; v -> vT
#pragma unroll
    for (int jj = 0; jj < 3; ++jj) {
      int gc = w * 48 + jj * 16;
      if (gc < 64) {             // k columns
        int hcol = gc + l15;
        float zl = 0.f;
#pragma unroll
        for (int rf = 0; rf < 4; ++rf)
#pragma unroll
          for (int r = 0; r < 4; ++r) {
            float ev = __expf(acc[rf][jj][r]);
            zl += ev;
            int n = rf * 16 + lg * 4 + r;
            int off = (hcol * 128 + n * 2) ^ ((hcol & 7) << 4);
            *(unsigned short*)(pTb + off) = f2bf(ev);
          }
        zl += __shfl_xor(zl, 16);
        zl += __shfl_xor(zl, 32);
        zacc[jj] += zl;
      } else if (gc < 128) {     // q columns -> store raw logits
        int hcol = gc - 64 + l15;
        float* qb = qbuf + ((size_t)bs * N_ + n0 + lg * 4) * 64 + hcol;
#pragma unroll
        for (int rf = 0; rf < 4; ++rf)
#pragma unroll
          for (int r = 0; r < 4; ++r)
            qb[(size_t)(rf * 16 + r) * 64] = acc[rf][jj][r];
      } else {                   // v columns
        int dcol = gc - 128 + l15;
#pragma unroll
        for (int rf = 0; rf < 4; ++rf)
#pragma unroll
          for (int r = 0; r < 4; ++r) {
            int n = rf * 16 + lg * 4 + r;
            int off = (dcol * 128 + n * 2) ^ ((dcol & 7) << 4);
            *(unsigned short*)(vTb + off) = f2bf(acc[rf][jj][r]);
          }
      }
    }
    __syncthreads();

    // phase 2: nw[h][d] += P^T V over this tile's 64 tokens
#pragma unroll
    for (int k2 = 0; k2 < 2; ++k2) {
      int hh = w * 16 + l15;
      int aoff = (hh * 128 + (k2 * 32 + lg * 8) * 2) ^ ((hh & 7) << 4);
      bf16x8 a2 = *(const bf16x8*)(pTb + aoff);
#pragma unroll
      for (int j2 = 0; j2 < 4; ++j2) {
        int dd = j2 * 16 + l15;
        int boff = (dd * 128 + (k2 * 32 + lg * 8) * 2) ^ ((dd & 7) << 4);
        bf16x8 b2 = *(const bf16x8*)(vTb + boff);
        nwacc[j2] = __builtin_amdgcn_mfma_f32_16x16x32_bf16(a2, b2, nwacc[j2], 0, 0, 0);
      }
    }
    __syncthreads();
  }

  // write partials
#pragma unroll
  for (int j2 = 0; j2 < 4; ++j2)
#pragma unroll
    for (int r = 0; r < 4; ++r) {
      int h = w * 16 + lg * 4 + r;
      int d = j2 * 16 + l15;
      pnw[(((size_t)bs * 64 + pb) * 64 + h) * 64 + d] = nwacc[j2][r];
    }
  if (lg == 0) {
#pragma unroll
    for (int jj = 0; jj < 3; ++jj) {
      int gc = w * 48 + jj * 16;
      if (gc < 64) pz[((size_t)bs * 64 + pb) * 64 + gc + l15] = zacc[jj];
    }
  }
}

__global__ __launch_bounds__(256) void kB_reduce(
    const float* __restrict__ pnw, const float* __restrict__ pz,
    float* __restrict__ wfin) {
  int g = blockIdx.x;   // 0..15: covers idx [g*256, g*256+256) => h in [g*4, g*4+4)
  int bs = blockIdx.y;  // 0..7
  int t = threadIdx.x;
  int wv = t >> 6, l = t & 63;
  __shared__ float zinv[4];
  int h = g * 4 + wv;
  float z = pz[((size_t)bs * 64 + l) * 64 + h];
#pragma unroll
  for (int m = 32; m; m >>= 1) z += __shfl_xor(z, m);
  if (l == 0) zinv[wv] = 1.f / z;
  __syncthreads();
  int idx = g * 256 + t;
  float ssum = 0.f;
  for (int p = 0; p < 64; ++p)
    ssum += pnw[((size_t)bs * 64 + p) * 4096 + idx];
  wfin[(size_t)bs * 4096 + idx] = ssum * zinv[wv];
}

__global__ __launch_bounds__(256) void kC_out(
    const float* __restrict__ qbuf, const float* __restrict__ wfin,
    float* __restrict__ out) {
  int bs = blockIdx.y, b = bs >> 1, s = bs & 1;
  __shared__ float wl[4096];
  const float* wsrc = wfin + (size_t)(b * 2 + (1 - s)) * 4096;  // cross: stream s uses w_{1-s}
  for (int i = threadIdx.x; i < 4096; i += 256) wl[i] = wsrc[i];
  __syncthreads();
  int t = threadIdx.x;
  int tok = blockIdx.x * 64 + (t >> 2);
  int p = t & 3;                 // quarter of the 64-dim output
  const f32x4* q = (const f32x4*)(qbuf + ((size_t)bs * N_ + tok) * 64);
  float e[64];
  float sum = 0.f;
#pragma unroll
  for (int i = 0; i < 16; ++i) {
    f32x4 qv = q[i];
#pragma unroll
    for (int r = 0; r < 4; ++r) {
      float ev = __expf(qv[r]);
      e[i * 4 + r] = ev;
      sum += ev;
    }
  }
  float inv = 1.f / sum;
  f32x4 o0 = {0,0,0,0}, o1 = {0,0,0,0}, o2 = {0,0,0,0}, o3 = {0,0,0,0};
#pragma unroll
  for (int hh = 0; hh < 64; ++hh) {
    float ph = e[hh] * inv;
    const f32x4* wr = (const f32x4*)&wl[hh * 64 + p * 16];
    o0 += ph * wr[0];
    o1 += ph * wr[1];
    o2 += ph * wr[2];
    o3 += ph * wr[3];
  }
  float* ob = out + (size_t)s * ((size_t)B_ * N_ * 64) + ((size_t)b * N_ + tok) * 64 + p * 16;
  f32x4* obv = (f32x4*)ob;
  obv[0] = o0; obv[1] = o1; obv[2] = o2; obv[3] = o3;
}

extern "C" void kernel_launch(void* const* d_in, const int* in_sizes, int n_in,
                              void* d_out, int out_size, void* d_ws, size_t ws_size,
                              hipStream_t stream) {
  const float* x0  = (const float*)d_in[0];
  const float* x1  = (const float*)d_in[1];
  const float* Wk0 = (const float*)d_in[2];
  const float* Wk1 = (const float*)d_in[3];
  const float* Wq0 = (const float*)d_in[4];
  const float* Wq1 = (const float*)d_in[5];
  const float* Wv0 = (const float*)d_in[6];
  const float* Wv1 = (const float*)d_in[7];
  float* out = (float*)d_out;
  char* wsb = (char*)d_ws;
  unsigned short* wpack = (unsigned short*)(wsb + WPACK_OFF);
  float* qbuf = (float*)(wsb + Q_OFF);
  float* pnw  = (float*)(wsb + PNW_OFF);
  float* pz   = (float*)(wsb + PZ_OFF);
  float* wfin = (float*)(wsb + WFIN_OFF);

  kW_pack<<<dim3(384), dim3(256), 0, stream>>>(Wk0, Wk1, Wq0, Wq1, Wv0, Wv1, wpack);
  kA_proj<<<dim3(64, 8), dim3(256), 0, stream>>>(x0, x1, wpack, qbuf, pnw, pz);
  kB_reduce<<<dim3(16, 8), dim3(256), 0, stream>>>(pnw, pz, wfin);
  kC_out<<<dim3(256, 8), dim3(256), 0, stream>>>(qbuf, wfin, out);
}